// Round 2
// baseline (390.211 us; speedup 1.0000x reference)
//
#include <hip/hip_runtime.h>
#include <math.h>

// A: (8,16,64,64,64) fp32; U: (8,16,2,64,64,64) fp32
// out: (8,80,64,64) fp32 = [A_last, A_fast, A_slow, A_deriv, E_temp] on ch axis.
// EMA split: fast_total = part(t=32..63) + 0.74^32 * part(t=0..31)  (linearity).
// Two blocks per (bm,split): h=0 handles t<32, h=1 handles t>=32 + epilogue.
// Combine via atomicAdd (exactly 2 commutative contributors -> deterministic),
// after a stream-ordered memset-0 of d_out.

#define T_DIM 64
#define HW    4096
#define HALF_T 32

typedef __attribute__((ext_vector_type(4))) float f4v;

__device__ __forceinline__ f4v ntload4(const float* p) {
    return __builtin_nontemporal_load((const f4v*)p);
}

__global__ __launch_bounds__(256, 4) void temporal_summarizer_kernel(
        const float* __restrict__ A, const float* __restrict__ U,
        float* __restrict__ out, float pf32, float ps32) {
    constexpr float AF = 0.74f, AS = 0.95f;
    constexpr float OMF = 1.0f - 0.74f, OMS = 1.0f - 0.95f;
    constexpr float EPS = 1e-6f;

    const int blk   = blockIdx.x;
    const int hh    = blk & 1;              // T-half
    const int split = (blk >> 1) & 3;       // plane quarter
    const int bm    = blk >> 3;             // 0..127
    const int m     = bm & 15;
    const int b     = bm >> 4;

    const int pix = split * (HW / 4) + threadIdx.x * 4;

    const float* pA = A + (size_t)bm * (T_DIM * HW) + (size_t)(hh * HALF_T) * HW + pix;

    f4v fast = 0.f, slow = 0.f;
    f4v a62 = 0.f, a63 = 0.f;

    #pragma unroll 16
    for (int t = 0; t < HALF_T; ++t) {
        f4v x = ntload4(pA + (size_t)t * HW);
        fast = AF * fast + OMF * x;
        slow = AS * slow + OMS * x;
        if (hh && t == HALF_T - 2) a62 = x;
        if (hh && t == HALF_T - 1) a63 = x;
    }

    if (!hh) {               // low half: scale partial by alpha^32
        fast *= pf32;
        slow *= ps32;
    }

    float* ofast = out + ((size_t)(b * 80 + 16 + m)) * HW + pix;
    float* oslow = out + ((size_t)(b * 80 + 32 + m)) * HW + pix;
    #pragma unroll
    for (int i = 0; i < 4; ++i) {
        atomicAdd(&ofast[i], fast[i]);
        atomicAdd(&oslow[i], slow[i]);
    }

    if (hh) {
        // epilogue: A_last, A_deriv, E_temp (only high-half blocks have t=62,63)
        const float* pU = U + (size_t)bm * (2 * T_DIM * HW) + pix;
        f4v u0l = ntload4(pU + 63 * HW);
        f4v u0m = ntload4(pU + 61 * HW);
        f4v u1l = ntload4(pU + (size_t)T_DIM * HW + 63 * HW);
        f4v u1m = ntload4(pU + (size_t)T_DIM * HW + 61 * HW);

        f4v et;
        #pragma unroll
        for (int i = 0; i < 4; ++i) {
            float pq0 = 0.5f * (u0l[i] - u0m[i]);
            float er  = sqrtf(fmaxf(u0l[i] * u0l[i] + pq0 * pq0, EPS));
            float pq1 = 0.5f * (u1l[i] - u1m[i]);
            float ei  = sqrtf(fmaxf(u1l[i] * u1l[i] + pq1 * pq1, EPS));
            et[i] = sqrtf(fmaxf(er * er + ei * ei, EPS));
        }

        f4v deriv = a63 - a62;

        float* ob = out + ((size_t)(b * 80 + m)) * HW + pix;
        *(f4v*)(ob + 0 * 16 * HW) = a63;    // A_last  (ch 0..15)
        *(f4v*)(ob + 48 * HW)     = deriv;  // A_deriv (ch 48..63)
        *(f4v*)(ob + 64 * HW)     = et;     // E_temp  (ch 64..79)
    }
}

extern "C" void kernel_launch(void* const* d_in, const int* in_sizes, int n_in,
                              void* d_out, int out_size, void* d_ws, size_t ws_size,
                              hipStream_t stream) {
    const float* A = (const float*)d_in[0];
    const float* U = (const float*)d_in[1];
    float* out = (float*)d_out;

    // zero the atomic-accumulated channels (whole out: one call, ~10.5 MB)
    hipMemsetAsync(out, 0, (size_t)out_size * sizeof(float), stream);

    const float pf32 = (float)pow(0.74, 32.0);   // exact-in-double alpha^32
    const float ps32 = (float)pow(0.95, 32.0);

    dim3 grid(8 * 16 * 4 * 2);   // 1024 blocks: (bm,split,half)
    dim3 block(256);
    temporal_summarizer_kernel<<<grid, block, 0, stream>>>(A, U, out, pf32, ps32);
}

// Round 3
// 366.183 us; speedup vs baseline: 1.0656x; 1.0656x over previous
//
#include <hip/hip_runtime.h>
#include <math.h>

// A: (8,16,64,64,64) fp32; U: (8,16,2,64,64,64) fp32
// out: (8,80,64,64) fp32 = [A_last, A_fast, A_slow, A_deriv, E_temp] on ch axis.
// Single kernel, one block per (bm, quarter-plane); each thread owns one float4
// of the plane and runs the EMA recurrence over t (mathematically identical to
// the reference weighted sum: acc_t = a*acc + (1-a)*x_t).
// Traffic floor: A 137 MB + U slices 8 MB + out 10.5 MB ~= 155 MB -> ~25 us.

#define T_DIM 64
#define HW    4096

typedef __attribute__((ext_vector_type(4))) float f4v;

__device__ __forceinline__ f4v ntload4(const float* p) {
    return __builtin_nontemporal_load((const f4v*)p);
}
__device__ __forceinline__ void ntstore4(float* p, f4v v) {
    __builtin_nontemporal_store(v, (f4v*)p);
}

__global__ __launch_bounds__(256) void temporal_summarizer_kernel(
        const float* __restrict__ A, const float* __restrict__ U,
        float* __restrict__ out) {
    constexpr float AF = 0.74f, AS = 0.95f;
    constexpr float OMF = 1.0f - 0.74f, OMS = 1.0f - 0.95f;
    constexpr float EPS = 1e-6f;

    const int blk   = blockIdx.x;
    const int split = blk & 3;              // plane quarter
    const int bm    = blk >> 2;             // 0..127
    const int m     = bm & 15;
    const int b     = bm >> 4;

    const int pix = split * (HW / 4) + threadIdx.x * 4;

    const float* pA = A + (size_t)bm * (T_DIM * HW) + pix;

    f4v fast = 0.f, slow = 0.f;
    f4v a62 = 0.f, a63 = 0.f;

    #pragma unroll
    for (int t = 0; t < T_DIM; ++t) {
        f4v x = ntload4(pA + (size_t)t * HW);
        fast = AF * fast + OMF * x;
        slow = AS * slow + OMS * x;
        if (t == T_DIM - 2) a62 = x;   // compile-time (full unroll)
        if (t == T_DIM - 1) a63 = x;
    }

    // U slices: c=0/1 at t=61 and t=63
    const float* pU = U + (size_t)bm * (2 * T_DIM * HW) + pix;
    f4v u0l = ntload4(pU + 63 * HW);
    f4v u0m = ntload4(pU + 61 * HW);
    f4v u1l = ntload4(pU + (size_t)T_DIM * HW + 63 * HW);
    f4v u1m = ntload4(pU + (size_t)T_DIM * HW + 61 * HW);

    f4v et;
    #pragma unroll
    for (int i = 0; i < 4; ++i) {
        float pq0 = 0.5f * (u0l[i] - u0m[i]);
        float er2 = fmaxf(u0l[i] * u0l[i] + pq0 * pq0, EPS);
        float pq1 = 0.5f * (u1l[i] - u1m[i]);
        float ei2 = fmaxf(u1l[i] * u1l[i] + pq1 * pq1, EPS);
        et[i] = sqrtf(fmaxf(er2 + ei2, EPS));   // sqrt(max(er^2+ei^2,eps)); er=sqrt(er2) etc.
    }
    // note: sqrt(er2)^2 == er2 exactly enough for fp32 threshold; keep explicit
    // two-stage form to match reference rounding:
    #pragma unroll
    for (int i = 0; i < 4; ++i) {
        float pq0 = 0.5f * (u0l[i] - u0m[i]);
        float er  = sqrtf(fmaxf(u0l[i] * u0l[i] + pq0 * pq0, EPS));
        float pq1 = 0.5f * (u1l[i] - u1m[i]);
        float ei  = sqrtf(fmaxf(u1l[i] * u1l[i] + pq1 * pq1, EPS));
        et[i] = sqrtf(fmaxf(er * er + ei * ei, EPS));
    }

    f4v deriv = a63 - a62;

    float* ob = out + ((size_t)(b * 80 + m)) * HW + pix;
    ntstore4(ob + 0 * 16 * HW, a63);    // A_last  (ch 0..15)
    ntstore4(ob + 1 * 16 * HW, fast);   // A_fast  (ch 16..31)
    ntstore4(ob + 2 * 16 * HW, slow);   // A_slow  (ch 32..47)
    ntstore4(ob + 3 * 16 * HW, deriv);  // A_deriv (ch 48..63)
    ntstore4(ob + 4 * 16 * HW, et);     // E_temp  (ch 64..79)
}

extern "C" void kernel_launch(void* const* d_in, const int* in_sizes, int n_in,
                              void* d_out, int out_size, void* d_ws, size_t ws_size,
                              hipStream_t stream) {
    const float* A = (const float*)d_in[0];
    const float* U = (const float*)d_in[1];
    float* out = (float*)d_out;
    dim3 grid(8 * 16 * 4);   // 512 blocks: (bm, quarter-plane)
    dim3 block(256);
    temporal_summarizer_kernel<<<grid, block, 0, stream>>>(A, U, out);
}